// Round 4
// baseline (1554.287 us; speedup 1.0000x reference)
//
#include <hip/hip_runtime.h>
#include <hip/hip_bf16.h>

#define B_  8
#define L_  4096
#define D_  1024
#define H_  16
#define MTOT (B_*L_)          // 32768
#define NFF  (4*D_)           // 4096
#define CH   4096             // attention chunk = one batch row

typedef __bf16 bf16_t;
typedef float  f32x4 __attribute__((ext_vector_type(4)));
typedef __bf16 b16x8 __attribute__((ext_vector_type(8)));
typedef __bf16 b16x4 __attribute__((ext_vector_type(4)));

// ---- workspace offsets (bytes). Weights [0,32MB), Xb [32,96MB), B-region at 96MB.
#define OFF_WQKVT ((size_t)0)                    // bf16 [3072][1024]  6 MB
#define OFF_WOT   ((size_t)6291456)              // bf16 [1024][1024]  2 MB
#define OFF_W1T   ((size_t)8388608)              // bf16 [4096][1024]  8 MB
#define OFF_W2T   ((size_t)16777216)             // bf16 [1024][4096]  8 MB
#define OFF_BQKV  ((size_t)25165824)             // fp32 [3072]
#define OFF_XB    ((size_t)33554432)             // bf16 [32768][1024] 64 MB (X+pe, later X1)
#define OFF_B     ((size_t)100663296)            // flexible region at 96 MB

// ---------------- X = bf16(X + pe) ----------------
__global__ __launch_bounds__(256) void k_add_pe(const float* __restrict__ X,
                                                const float* __restrict__ pe,
                                                bf16_t* __restrict__ Xb)
{
    size_t i  = ((size_t)blockIdx.x * 256 + threadIdx.x) * 4;
    size_t ld = i & ((size_t)L_ * D_ - 1);
    float4 x = *(const float4*)(X + i);
    float4 p = *(const float4*)(pe + ld);
    b16x4 b;
    b[0] = (bf16_t)(x.x + p.x); b[1] = (bf16_t)(x.y + p.y);
    b[2] = (bf16_t)(x.z + p.z); b[3] = (bf16_t)(x.w + p.w);
    *(b16x4*)(Xb + i) = b;
}

// ---------------- fused weight prep: 6 transposes + bias concat ----------------
__global__ __launch_bounds__(256) void k_prep(const float* __restrict__ Wq,
                                              const float* __restrict__ Wk,
                                              const float* __restrict__ Wv,
                                              const float* __restrict__ Wo,
                                              const float* __restrict__ W1,
                                              const float* __restrict__ W2,
                                              const float* __restrict__ bq,
                                              const float* __restrict__ bk,
                                              const float* __restrict__ bv,
                                              bf16_t* __restrict__ WqkvT,
                                              bf16_t* __restrict__ WoT,
                                              bf16_t* __restrict__ W1T,
                                              bf16_t* __restrict__ W2T,
                                              float* __restrict__ bqkv)
{
    const int id = blockIdx.x;
    if (id >= 12288) {                       // bias concat
        const int i = (id - 12288) * 256 + threadIdx.x;
        if (i < 1024)       bqkv[i] = bq[i];
        else if (i < 2048)  bqkv[i] = bk[i - 1024];
        else if (i < 3072)  bqkv[i] = bv[i - 2048];
        return;
    }
    const float* src; bf16_t* dst; int K, N, t;
    if (id < 4096) {
        const int w = id >> 10; t = id & 1023; K = 1024; N = 1024;
        src = (w == 0) ? Wq : (w == 1) ? Wk : (w == 2) ? Wv : Wo;
        dst = (w < 3) ? (WqkvT + (size_t)w * 1024 * 1024) : WoT;
    } else if (id < 8192) {
        t = id - 4096; K = 1024; N = 4096; src = W1; dst = W1T;
    } else {
        t = id - 8192; K = 4096; N = 1024; src = W2; dst = W2T;
    }
    const int ntiles = N >> 5;
    const int n0 = (t % ntiles) << 5;
    const int k0 = (t / ntiles) << 5;

    __shared__ float tt[32][33];
    const int tx = threadIdx.x & 31;
    const int ty = threadIdx.x >> 5;
    #pragma unroll
    for (int i = ty; i < 32; i += 8)
        tt[i][tx] = src[(size_t)(k0 + i) * N + n0 + tx];
    __syncthreads();
    #pragma unroll
    for (int i = ty; i < 32; i += 8)
        dst[(size_t)(n0 + i) * K + k0 + tx] = (bf16_t)tt[tx][i];
}

// ---------------- m97-style bf16 GEMM with XOR-swizzled LDS ----------------
#define BM 128
#define BN 128
#define BK 32

__device__ __forceinline__ void gload_lds16(const void* g, char* lds_byte) {
    __builtin_amdgcn_global_load_lds((const __attribute__((address_space(1))) void*)g,
                                     (__attribute__((address_space(3))) void*)lds_byte,
                                     16, 0, 0);
}

// LDS layout: row r (64 B = 4 slots of 16 B); global chunk c lives at slot
// c ^ swz(r&15), swz(r) = (r&3)^((r>>2)&3). Staged via lane-chunk permutation
// (global_load_lds dst is fixed lane*16), read back with the same swizzle.
// Per 8-lane phase the read bank-groups tile all 32 banks -> conflict-free.

// EPI: 0 = fp32 out, 1 = bf16 out, 2 = relu -> bf16 out
template<int EPI>
__global__ __launch_bounds__(256, 4) void k_gemm_bt(const bf16_t* __restrict__ A,
                                                    const bf16_t* __restrict__ Bt,
                                                    const float* __restrict__ bias,
                                                    void* __restrict__ Cv,
                                                    const int N, const int K)
{
    __shared__ __align__(16) bf16_t As[BM * BK];
    __shared__ __align__(16) bf16_t Bs[BN * BK];
    const int tid  = threadIdx.x;
    const int wave = tid >> 6;
    const int lane = tid & 63;

    // XCD-aware swizzle (R3: kills cross-XCD A over-fetch).
    const int Nt = gridDim.x, Mt = gridDim.y;
    const int lid = blockIdx.y * Nt + blockIdx.x;
    int bm, bn;
    {
        const int xcd = lid & 7;
        const int s   = lid >> 3;
        bm = xcd * (Mt >> 3) + s / Nt;
        bn = s % Nt;
    }
    const int n0 = bn * BN;
    const int m0 = bm * BM;
    const int waveM = wave >> 1;
    const int waveN = wave & 1;

    // staging: lane l stages row (tid>>2), chunk (l&3)^((l>>2)&3)^((l>>4)&3)
    const int srow   = tid >> 2;
    const int schunk = (tid & 3) ^ ((tid >> 2) & 3) ^ ((tid >> 4) & 3);
    const int scol   = schunk << 3;
    const bf16_t* ag  = A  + (size_t)(m0 + srow)      * K + scol;
    const bf16_t* ag2 = A  + (size_t)(m0 + 64 + srow) * K + scol;
    const bf16_t* bg  = Bt + (size_t)(n0 + srow)      * K + scol;
    const bf16_t* bg2 = Bt + (size_t)(n0 + 64 + srow) * K + scol;

    char* ldsA = (char*)&As[0] + wave * 1024;    // wave-uniform base; HW adds lane*16
    char* ldsB = (char*)&Bs[0] + wave * 1024;

    // reader: row = waveX*64 + (lane&15) + 16*i; row&15 == lane&15 for all i,
    // so slot = (lane>>4) ^ (lane&3) ^ ((lane>>2)&3) is loop-invariant.
    const int slot = (lane >> 4) ^ (lane & 3) ^ ((lane >> 2) & 3);
    const bf16_t* AsP = As + (waveM * 64 + (lane & 15)) * BK + slot * 8;
    const bf16_t* BsP = Bs + (waveN * 64 + (lane & 15)) * BK + slot * 8;

    f32x4 acc[4][4] = {};

    for (int kt = 0; kt < K; kt += BK) {
        __syncthreads();
        gload_lds16(ag,  ldsA);
        gload_lds16(ag2, ldsA + 4096);
        gload_lds16(bg,  ldsB);
        gload_lds16(bg2, ldsB + 4096);
        ag += BK; ag2 += BK; bg += BK; bg2 += BK;
        __syncthreads();
        b16x8 af[4], bfr[4];
        #pragma unroll
        for (int i = 0; i < 4; ++i) af[i]  = *(const b16x8*)(AsP + i * 16 * BK);
        #pragma unroll
        for (int i = 0; i < 4; ++i) bfr[i] = *(const b16x8*)(BsP + i * 16 * BK);
        #pragma unroll
        for (int mi = 0; mi < 4; ++mi)
            #pragma unroll
            for (int ni = 0; ni < 4; ++ni)
                acc[mi][ni] = __builtin_amdgcn_mfma_f32_16x16x32_bf16(af[mi], bfr[ni], acc[mi][ni], 0, 0, 0);
    }

    const int rbase = m0 + waveM * 64 + ((lane >> 4) << 2);
    const int cbase = n0 + waveN * 64 + (lane & 15);
    #pragma unroll
    for (int mi = 0; mi < 4; ++mi) {
        #pragma unroll
        for (int ni = 0; ni < 4; ++ni) {
            const int col = cbase + ni * 16;
            const float bb = bias[col];
            #pragma unroll
            for (int r = 0; r < 4; ++r) {
                const int rowg = rbase + mi * 16 + r;
                float v = acc[mi][ni][r] + bb;
                if (EPI == 2) v = fmaxf(v, 0.0f);
                if (EPI == 0) ((float*)Cv)[(size_t)rowg * N + col] = v;
                else          ((bf16_t*)Cv)[(size_t)rowg * N + col] = (bf16_t)v;
            }
        }
    }
}

// ---------------- window-3 attention, one chunk = one batch (4096 rows) ----------------
__global__ __launch_bounds__(256) void k_attn(const bf16_t* __restrict__ QKV, // [4096][3072]
                                              const unsigned char* __restrict__ mask, // [4096]
                                              bf16_t* __restrict__ ctx)       // [4096][1024]
{
    const int wid  = (blockIdx.x << 2) + (threadIdx.x >> 6);
    const int lane = threadIdx.x & 63;
    const int h    = wid & (H_ - 1);
    const int l    = wid >> 4;           // local row 0..4095

    const float q = (float)QKV[(size_t)l * 3072 + h * 64 + lane];
    float sc[3], vv[3];
    bool  ok[3];
    #pragma unroll
    for (int w = 0; w < 3; ++w) {
        const int lw  = l + w - 1;
        const bool valid = (unsigned)lw < (unsigned)L_;
        const int lwc = lw < 0 ? 0 : (lw > L_ - 1 ? L_ - 1 : lw);
        const size_t rb = (size_t)lwc * 3072 + h * 64 + lane;
        const float kk = (float)QKV[rb + 1024];
        vv[w] = (float)QKV[rb + 2048];
        ok[w] = valid && (mask[lwc] == 0);
        sc[w] = q * kk;
    }
    #pragma unroll
    for (int off = 32; off; off >>= 1) {
        sc[0] += __shfl_xor(sc[0], off);
        sc[1] += __shfl_xor(sc[1], off);
        sc[2] += __shfl_xor(sc[2], off);
    }
    const float s0 = ok[0] ? sc[0] * 0.125f : -1e30f;
    const float s1 = ok[1] ? sc[1] * 0.125f : -1e30f;
    const float s2 = ok[2] ? sc[2] * 0.125f : -1e30f;
    const float mx = fmaxf(s0, fmaxf(s1, s2));
    const float e0 = __expf(s0 - mx), e1 = __expf(s1 - mx), e2 = __expf(s2 - mx);
    const float inv = 1.0f / (e0 + e1 + e2);
    const float o = (e0 * vv[0] + e1 * vv[1] + e2 * vv[2]) * inv;
    ctx[(size_t)l * 1024 + h * 64 + lane] = (bf16_t)o;
}

// ---------------- residual(bf16) + Y(fp32) -> layernorm ----------------
template<int FINAL>
__global__ __launch_bounds__(256) void k_res_ln(const bf16_t* __restrict__ Xres,
                                                const float* __restrict__ Y,
                                                const float* __restrict__ g,
                                                const float* __restrict__ beta,
                                                bf16_t* __restrict__ outB,
                                                float* __restrict__ outF)
{
    const int row = blockIdx.x;
    const int tid = threadIdx.x;
    const size_t base = (size_t)row * D_ + tid * 4;
    b16x4  xr = *(const b16x4*)(Xres + base);
    float4 y  = *(const float4*)(Y + base);
    const float t0 = (float)xr[0] + y.x, t1 = (float)xr[1] + y.y;
    const float t2 = (float)xr[2] + y.z, t3 = (float)xr[3] + y.w;
    float s = t0 + t1 + t2 + t3;
    float q = t0*t0 + t1*t1 + t2*t2 + t3*t3;
    #pragma unroll
    for (int off = 32; off; off >>= 1) {
        s += __shfl_xor(s, off);
        q += __shfl_xor(q, off);
    }
    __shared__ float red[8];
    const int wv = tid >> 6, ln = tid & 63;
    if (ln == 0) { red[wv] = s; red[wv + 4] = q; }
    __syncthreads();
    s = red[0] + red[1] + red[2] + red[3];
    q = red[4] + red[5] + red[6] + red[7];
    const float mean = s * (1.0f / D_);
    const float var  = q * (1.0f / D_) - mean * mean;
    const float rs   = rsqrtf(var + 1e-5f);
    const int c = tid * 4;
    float4 gv = *(const float4*)(g + c);
    float4 bv = *(const float4*)(beta + c);
    float o0 = (t0 - mean) * rs * gv.x + bv.x;
    float o1 = (t1 - mean) * rs * gv.y + bv.y;
    float o2 = (t2 - mean) * rs * gv.z + bv.z;
    float o3 = (t3 - mean) * rs * gv.w + bv.w;
    if (FINAL) {
        float4 o; o.x = o0; o.y = o1; o.z = o2; o.w = o3;
        *(float4*)(outF + base) = o;
    } else {
        b16x4 b; b[0] = (bf16_t)o0; b[1] = (bf16_t)o1; b[2] = (bf16_t)o2; b[3] = (bf16_t)o3;
        *(b16x4*)(outB + base) = b;
    }
}

extern "C" void kernel_launch(void* const* d_in, const int* in_sizes, int n_in,
                              void* d_out, int out_size, void* d_ws, size_t ws_size,
                              hipStream_t stream)
{
    const float* X    = (const float*)d_in[0];
    const unsigned char* mask = (const unsigned char*)d_in[1];
    const float* pe   = (const float*)d_in[2];
    const float* Wq   = (const float*)d_in[3];
    const float* Wk   = (const float*)d_in[4];
    const float* Wv   = (const float*)d_in[5];
    const float* bq   = (const float*)d_in[6];
    const float* bk   = (const float*)d_in[7];
    const float* bv   = (const float*)d_in[8];
    const float* Wo   = (const float*)d_in[9];
    const float* bo   = (const float*)d_in[10];
    const float* g1   = (const float*)d_in[11];
    const float* be1  = (const float*)d_in[12];
    const float* W1   = (const float*)d_in[13];
    const float* b1   = (const float*)d_in[14];
    const float* W2   = (const float*)d_in[15];
    const float* b2   = (const float*)d_in[16];
    const float* g2   = (const float*)d_in[17];
    const float* be2  = (const float*)d_in[18];

    char* ws = (char*)d_ws;
    bf16_t* WqkvT = (bf16_t*)(ws + OFF_WQKVT);
    bf16_t* WoT   = (bf16_t*)(ws + OFF_WOT);
    bf16_t* W1T   = (bf16_t*)(ws + OFF_W1T);
    bf16_t* W2T   = (bf16_t*)(ws + OFF_W2T);
    float*  bqkv  = (float*) (ws + OFF_BQKV);
    bf16_t* Xb    = (bf16_t*)(ws + OFF_XB);
    float*  Y     = (float*)d_out;            // d_out doubles as fp32 GEMM-out scratch

    const bool big = ws_size >= (size_t)234881024;

    // 1. Xb = bf16(X + pe)
    k_add_pe<<<MTOT * D_ / 1024, 256, 0, stream>>>(X, pe, Xb);

    // 2. fused weight prep
    k_prep<<<12300, 256, 0, stream>>>(Wq, Wk, Wv, Wo, W1, W2, bq, bk, bv,
                                      WqkvT, WoT, W1T, W2T, bqkv);

    if (big) {
        bf16_t* ctx  = (bf16_t*)(ws + OFF_B);              // 64 MB [96,160)
        bf16_t* qkvc = (bf16_t*)(ws + OFF_B + 67108864);   // 24 MB [160,184)
        for (int b = 0; b < B_; ++b) {
            k_gemm_bt<1><<<dim3(3072/BN, CH/BM), 256, 0, stream>>>(
                Xb + (size_t)b*CH*D_, WqkvT, bqkv, qkvc, 3072, 1024);
            k_attn<<<CH*H_/4, 256, 0, stream>>>(qkvc, mask + (size_t)b*CH,
                                                ctx + (size_t)b*CH*D_);
        }
        k_gemm_bt<0><<<dim3(1024/BN, MTOT/BM), 256, 0, stream>>>(ctx, WoT, bo, Y, 1024, 1024);
        k_res_ln<0><<<MTOT, 256, 0, stream>>>(Xb, Y, g1, be1, Xb, nullptr);
        bf16_t* hb = (bf16_t*)(ws + OFF_B);                // 128 MB [96,224)
        for (int c = 0; c < 2; ++c) {
            const size_t r0 = (size_t)c * 16384;
            k_gemm_bt<2><<<dim3(NFF/BN, 16384/BM), 256, 0, stream>>>(
                Xb + r0*D_, W1T, b1, hb, NFF, 1024);
            k_gemm_bt<0><<<dim3(1024/BN, 16384/BM), 256, 0, stream>>>(
                hb, W2T, b2, Y + r0*D_, 1024, NFF);
        }
        k_res_ln<1><<<MTOT, 256, 0, stream>>>(Xb, Y, g2, be2, nullptr, (float*)d_out);
    } else {
        bf16_t* qkvc = (bf16_t*)(ws + OFF_B);              // 24 MB [96,120)
        bf16_t* ctxc = (bf16_t*)(ws + OFF_B + 25165824);   //  8 MB [120,128)
        for (int b = 0; b < B_; ++b) {
            const size_t r0 = (size_t)b * CH;
            k_gemm_bt<1><<<dim3(3072/BN, CH/BM), 256, 0, stream>>>(
                Xb + r0*D_, WqkvT, bqkv, qkvc, 3072, 1024);
            k_attn<<<CH*H_/4, 256, 0, stream>>>(qkvc, mask + r0, ctxc);
            k_gemm_bt<0><<<dim3(1024/BN, CH/BM), 256, 0, stream>>>(
                ctxc, WoT, bo, Y + r0*D_, 1024, 1024);
        }
        k_res_ln<0><<<MTOT, 256, 0, stream>>>(Xb, Y, g1, be1, Xb, nullptr);
        bf16_t* hb = (bf16_t*)(ws + OFF_B);                // 32 MB [96,128)
        for (int c = 0; c < 8; ++c) {
            const size_t r0 = (size_t)c * CH;
            k_gemm_bt<2><<<dim3(NFF/BN, CH/BM), 256, 0, stream>>>(
                Xb + r0*D_, W1T, b1, hb, NFF, 1024);
            k_gemm_bt<0><<<dim3(1024/BN, CH/BM), 256, 0, stream>>>(
                hb, W2T, b2, Y + r0*D_, 1024, NFF);
        }
        k_res_ln<1><<<MTOT, 256, 0, stream>>>(Xb, Y, g2, be2, nullptr, (float*)d_out);
    }
}

// Round 5
// 1383.107 us; speedup vs baseline: 1.1238x; 1.1238x over previous
//
#include <hip/hip_runtime.h>
#include <hip/hip_bf16.h>

#define B_  8
#define L_  4096
#define D_  1024
#define H_  16
#define MTOT (B_*L_)          // 32768
#define NFF  (4*D_)           // 4096

typedef __bf16 bf16_t;
typedef float  f32x4 __attribute__((ext_vector_type(4)));
typedef __bf16 b16x8 __attribute__((ext_vector_type(8)));
typedef __bf16 b16x4 __attribute__((ext_vector_type(4)));

// ---- workspace offsets (bytes). Weights [0,32MB), Xb [32,96MB), B-region at 96MB.
#define OFF_WQKVT ((size_t)0)                    // bf16 [3072][1024]  6 MB
#define OFF_WOT   ((size_t)6291456)              // bf16 [1024][1024]  2 MB
#define OFF_W1T   ((size_t)8388608)              // bf16 [4096][1024]  8 MB
#define OFF_W2T   ((size_t)16777216)             // bf16 [1024][4096]  8 MB
#define OFF_BQKV  ((size_t)25165824)             // fp32 [3072]
#define OFF_XB    ((size_t)33554432)             // bf16 [32768][1024] 64 MB (X+pe, later X1)
#define OFF_B     ((size_t)100663296)            // flexible region at 96 MB

// ---------------- X = bf16(X + pe) ----------------
__global__ __launch_bounds__(256) void k_add_pe(const float* __restrict__ X,
                                                const float* __restrict__ pe,
                                                bf16_t* __restrict__ Xb)
{
    size_t i  = ((size_t)blockIdx.x * 256 + threadIdx.x) * 4;
    size_t ld = i & ((size_t)L_ * D_ - 1);
    float4 x = *(const float4*)(X + i);
    float4 p = *(const float4*)(pe + ld);
    b16x4 b;
    b[0] = (bf16_t)(x.x + p.x); b[1] = (bf16_t)(x.y + p.y);
    b[2] = (bf16_t)(x.z + p.z); b[3] = (bf16_t)(x.w + p.w);
    *(b16x4*)(Xb + i) = b;
}

// ---------------- fused weight prep: 6 transposes + bias concat ----------------
__global__ __launch_bounds__(256) void k_prep(const float* __restrict__ Wq,
                                              const float* __restrict__ Wk,
                                              const float* __restrict__ Wv,
                                              const float* __restrict__ Wo,
                                              const float* __restrict__ W1,
                                              const float* __restrict__ W2,
                                              const float* __restrict__ bq,
                                              const float* __restrict__ bk,
                                              const float* __restrict__ bv,
                                              bf16_t* __restrict__ WqkvT,
                                              bf16_t* __restrict__ WoT,
                                              bf16_t* __restrict__ W1T,
                                              bf16_t* __restrict__ W2T,
                                              float* __restrict__ bqkv)
{
    const int id = blockIdx.x;
    if (id >= 12288) {                       // bias concat
        const int i = (id - 12288) * 256 + threadIdx.x;
        if (i < 1024)       bqkv[i] = bq[i];
        else if (i < 2048)  bqkv[i] = bk[i - 1024];
        else if (i < 3072)  bqkv[i] = bv[i - 2048];
        return;
    }
    const float* src; bf16_t* dst; int K, N, t;
    if (id < 4096) {
        const int w = id >> 10; t = id & 1023; K = 1024; N = 1024;
        src = (w == 0) ? Wq : (w == 1) ? Wk : (w == 2) ? Wv : Wo;
        dst = (w < 3) ? (WqkvT + (size_t)w * 1024 * 1024) : WoT;
    } else if (id < 8192) {
        t = id - 4096; K = 1024; N = 4096; src = W1; dst = W1T;
    } else {
        t = id - 8192; K = 4096; N = 1024; src = W2; dst = W2T;
    }
    const int ntiles = N >> 5;
    const int n0 = (t % ntiles) << 5;
    const int k0 = (t / ntiles) << 5;

    __shared__ float tt[32][33];
    const int tx = threadIdx.x & 31;
    const int ty = threadIdx.x >> 5;
    #pragma unroll
    for (int i = ty; i < 32; i += 8)
        tt[i][tx] = src[(size_t)(k0 + i) * N + n0 + tx];
    __syncthreads();
    #pragma unroll
    for (int i = ty; i < 32; i += 8)
        dst[(size_t)(n0 + i) * K + k0 + tx] = (bf16_t)tt[tx][i];
}

// ---------------- bf16 GEMM, BK=64, XOR-swizzled LDS ----------------
// LDS row = 64 bf16 = 128 B = 8 chunks of 16 B. Chunk c of row r stored at
// slot c^(r&7) (row stride 128 B aliases all rows to the same banks, so the
// swizzle is REQUIRED here: per 8-lane phase the slots span 0..7 -> 32 banks).
#define BM 128
#define BN 128
#define BK 64

__device__ __forceinline__ void gload_lds16(const void* g, char* lds_byte) {
    __builtin_amdgcn_global_load_lds((const __attribute__((address_space(1))) void*)g,
                                     (__attribute__((address_space(3))) void*)lds_byte,
                                     16, 0, 0);
}

// EPI: 0 = fp32 out, 1 = bf16 out, 2 = relu -> bf16 out
template<int EPI>
__global__ __launch_bounds__(256, 4) void k_gemm_bt(const bf16_t* __restrict__ A,
                                                    const bf16_t* __restrict__ Bt,
                                                    const float* __restrict__ bias,
                                                    void* __restrict__ Cv,
                                                    const int N, const int K)
{
    __shared__ __align__(16) bf16_t As[BM * BK];   // 16 KB
    __shared__ __align__(16) bf16_t Bs[BN * BK];   // 16 KB
    const int tid  = threadIdx.x;
    const int wave = tid >> 6;
    const int lane = tid & 63;

    // XCD-aware swizzle (R3: each XCD gets a contiguous M-strip).
    const int Nt = gridDim.x, Mt = gridDim.y;
    const int lid = blockIdx.y * Nt + blockIdx.x;
    int bm, bn;
    {
        const int xcd = lid & 7;
        const int s   = lid >> 3;
        bm = xcd * (Mt >> 3) + s / Nt;
        bn = s % Nt;
    }
    const int n0 = bn * BN;
    const int m0 = bm * BM;
    const int waveM = wave >> 1;
    const int waveN = wave & 1;

    // staging: call c covers rows c*32..c*32+31; thread stages row c*32+(tid>>3),
    // LDS slot tid&7 -> fetch global chunk (tid&7)^((tid>>3)&7).
    const int srow   = tid >> 3;
    const int schunk = (tid & 7) ^ (srow & 7);
    const bf16_t* ag = A  + (size_t)(m0 + srow) * K + schunk * 8;
    const bf16_t* bg = Bt + (size_t)(n0 + srow) * K + schunk * 8;
    const size_t rstep = (size_t)32 * K;         // +32 rows
    char* ldsA = (char*)&As[0] + wave * 1024;    // + c*4096; HW adds lane*16
    char* ldsB = (char*)&Bs[0] + wave * 1024;

    // reader: row = waveX*64 + (lane&15) + 16*mi; row&7 == lane&7.
    // K-half s, quad q=lane>>4 wants global chunk s*4+q -> slot (s*4+q)^(lane&7).
    const int q   = lane >> 4;
    const int x7  = lane & 7;
    const int sl0 = ((q)     ^ x7) << 3;   // elem offset, s=0
    const int sl1 = ((4 + q) ^ x7) << 3;   // s=1
    const bf16_t* AsP = As + (waveM * 64 + (lane & 15)) * BK;
    const bf16_t* BsP = Bs + (waveN * 64 + (lane & 15)) * BK;

    f32x4 acc[4][4] = {};

    for (int kt = 0; kt < K; kt += BK) {
        __syncthreads();
        #pragma unroll
        for (int c = 0; c < 4; ++c) {
            gload_lds16(ag + c * rstep, ldsA + c * 4096);
            gload_lds16(bg + c * rstep, ldsB + c * 4096);
        }
        ag += BK; bg += BK;
        __syncthreads();
        b16x8 af[4], bfr[4];
        // K-half 0
        #pragma unroll
        for (int i = 0; i < 4; ++i) af[i]  = *(const b16x8*)(AsP + i * 16 * BK + sl0);
        #pragma unroll
        for (int i = 0; i < 4; ++i) bfr[i] = *(const b16x8*)(BsP + i * 16 * BK + sl0);
        #pragma unroll
        for (int mi = 0; mi < 4; ++mi)
            #pragma unroll
            for (int ni = 0; ni < 4; ++ni)
                acc[mi][ni] = __builtin_amdgcn_mfma_f32_16x16x32_bf16(af[mi], bfr[ni], acc[mi][ni], 0, 0, 0);
        // K-half 1
        #pragma unroll
        for (int i = 0; i < 4; ++i) af[i]  = *(const b16x8*)(AsP + i * 16 * BK + sl1);
        #pragma unroll
        for (int i = 0; i < 4; ++i) bfr[i] = *(const b16x8*)(BsP + i * 16 * BK + sl1);
        #pragma unroll
        for (int mi = 0; mi < 4; ++mi)
            #pragma unroll
            for (int ni = 0; ni < 4; ++ni)
                acc[mi][ni] = __builtin_amdgcn_mfma_f32_16x16x32_bf16(af[mi], bfr[ni], acc[mi][ni], 0, 0, 0);
    }

    const int rbase = m0 + waveM * 64 + ((lane >> 4) << 2);
    const int cbase = n0 + waveN * 64 + (lane & 15);
    #pragma unroll
    for (int mi = 0; mi < 4; ++mi) {
        #pragma unroll
        for (int ni = 0; ni < 4; ++ni) {
            const int col = cbase + ni * 16;
            const float bb = bias[col];
            #pragma unroll
            for (int r = 0; r < 4; ++r) {
                const int rowg = rbase + mi * 16 + r;
                float v = acc[mi][ni][r] + bb;
                if (EPI == 2) v = fmaxf(v, 0.0f);
                if (EPI == 0) ((float*)Cv)[(size_t)rowg * N + col] = v;
                else          ((bf16_t*)Cv)[(size_t)rowg * N + col] = (bf16_t)v;
            }
        }
    }
}

// ---------------- window-3 attention over a chunk of whole batches ----------------
__global__ __launch_bounds__(256) void k_attn(const bf16_t* __restrict__ QKV, // [rows][3072]
                                              const unsigned char* __restrict__ mask, // [rows]
                                              bf16_t* __restrict__ ctx)       // [rows][1024]
{
    const int wid  = (blockIdx.x << 2) + (threadIdx.x >> 6);
    const int lane = threadIdx.x & 63;
    const int h    = wid & (H_ - 1);
    const int l    = wid >> 4;           // chunk-local row
    const int lb   = l & (L_ - 1);       // batch-local position (chunks are whole batches)

    const float qv = (float)QKV[(size_t)l * 3072 + h * 64 + lane];
    float sc[3], vv[3];
    bool  ok[3];
    #pragma unroll
    for (int w = 0; w < 3; ++w) {
        const int d   = w - 1;
        const bool valid = (unsigned)(lb + d) < (unsigned)L_;
        const int dc  = valid ? d : 0;
        const size_t rb = (size_t)(l + dc) * 3072 + h * 64 + lane;
        const float kk = (float)QKV[rb + 1024];
        vv[w] = (float)QKV[rb + 2048];
        ok[w] = valid && (mask[l + dc] == 0);
        sc[w] = qv * kk;
    }
    #pragma unroll
    for (int off = 32; off; off >>= 1) {
        sc[0] += __shfl_xor(sc[0], off);
        sc[1] += __shfl_xor(sc[1], off);
        sc[2] += __shfl_xor(sc[2], off);
    }
    const float s0 = ok[0] ? sc[0] * 0.125f : -1e30f;
    const float s1 = ok[1] ? sc[1] * 0.125f : -1e30f;
    const float s2 = ok[2] ? sc[2] * 0.125f : -1e30f;
    const float mx = fmaxf(s0, fmaxf(s1, s2));
    const float e0 = __expf(s0 - mx), e1 = __expf(s1 - mx), e2 = __expf(s2 - mx);
    const float inv = 1.0f / (e0 + e1 + e2);
    const float o = (e0 * vv[0] + e1 * vv[1] + e2 * vv[2]) * inv;
    ctx[(size_t)l * 1024 + h * 64 + lane] = (bf16_t)o;
}

// ---------------- residual(bf16) + Y(fp32) -> layernorm ----------------
template<int FINAL>
__global__ __launch_bounds__(256) void k_res_ln(const bf16_t* __restrict__ Xres,
                                                const float* __restrict__ Y,
                                                const float* __restrict__ g,
                                                const float* __restrict__ beta,
                                                bf16_t* __restrict__ outB,
                                                float* __restrict__ outF)
{
    const int row = blockIdx.x;
    const int tid = threadIdx.x;
    const size_t base = (size_t)row * D_ + tid * 4;
    b16x4  xr = *(const b16x4*)(Xres + base);
    float4 y  = *(const float4*)(Y + base);
    const float t0 = (float)xr[0] + y.x, t1 = (float)xr[1] + y.y;
    const float t2 = (float)xr[2] + y.z, t3 = (float)xr[3] + y.w;
    float s = t0 + t1 + t2 + t3;
    float q = t0*t0 + t1*t1 + t2*t2 + t3*t3;
    #pragma unroll
    for (int off = 32; off; off >>= 1) {
        s += __shfl_xor(s, off);
        q += __shfl_xor(q, off);
    }
    __shared__ float red[8];
    const int wv = tid >> 6, ln = tid & 63;
    if (ln == 0) { red[wv] = s; red[wv + 4] = q; }
    __syncthreads();
    s = red[0] + red[1] + red[2] + red[3];
    q = red[4] + red[5] + red[6] + red[7];
    const float mean = s * (1.0f / D_);
    const float var  = q * (1.0f / D_) - mean * mean;
    const float rs   = rsqrtf(var + 1e-5f);
    const int c = tid * 4;
    float4 gv = *(const float4*)(g + c);
    float4 bv = *(const float4*)(beta + c);
    float o0 = (t0 - mean) * rs * gv.x + bv.x;
    float o1 = (t1 - mean) * rs * gv.y + bv.y;
    float o2 = (t2 - mean) * rs * gv.z + bv.z;
    float o3 = (t3 - mean) * rs * gv.w + bv.w;
    if (FINAL) {
        float4 o; o.x = o0; o.y = o1; o.z = o2; o.w = o3;
        *(float4*)(outF + base) = o;
    } else {
        b16x4 b; b[0] = (bf16_t)o0; b[1] = (bf16_t)o1; b[2] = (bf16_t)o2; b[3] = (bf16_t)o3;
        *(b16x4*)(outB + base) = b;
    }
}

extern "C" void kernel_launch(void* const* d_in, const int* in_sizes, int n_in,
                              void* d_out, int out_size, void* d_ws, size_t ws_size,
                              hipStream_t stream)
{
    const float* X    = (const float*)d_in[0];
    const unsigned char* mask = (const unsigned char*)d_in[1];
    const float* pe   = (const float*)d_in[2];
    const float* Wq   = (const float*)d_in[3];
    const float* Wk   = (const float*)d_in[4];
    const float* Wv   = (const float*)d_in[5];
    const float* bq   = (const float*)d_in[6];
    const float* bk   = (const float*)d_in[7];
    const float* bv   = (const float*)d_in[8];
    const float* Wo   = (const float*)d_in[9];
    const float* bo   = (const float*)d_in[10];
    const float* g1   = (const float*)d_in[11];
    const float* be1  = (const float*)d_in[12];
    const float* W1   = (const float*)d_in[13];
    const float* b1   = (const float*)d_in[14];
    const float* W2   = (const float*)d_in[15];
    const float* b2   = (const float*)d_in[16];
    const float* g2   = (const float*)d_in[17];
    const float* be2  = (const float*)d_in[18];

    char* ws = (char*)d_ws;
    bf16_t* WqkvT = (bf16_t*)(ws + OFF_WQKVT);
    bf16_t* WoT   = (bf16_t*)(ws + OFF_WOT);
    bf16_t* W1T   = (bf16_t*)(ws + OFF_W1T);
    bf16_t* W2T   = (bf16_t*)(ws + OFF_W2T);
    float*  bqkv  = (float*) (ws + OFF_BQKV);
    bf16_t* Xb    = (bf16_t*)(ws + OFF_XB);
    float*  Y     = (float*)d_out;            // d_out doubles as fp32 GEMM-out scratch

    const bool big = ws_size >= (size_t)234881024;

    // 1. Xb = bf16(X + pe)
    k_add_pe<<<MTOT * D_ / 1024, 256, 0, stream>>>(X, pe, Xb);

    // 2. fused weight prep
    k_prep<<<12300, 256, 0, stream>>>(Wq, Wk, Wv, Wo, W1, W2, bq, bk, bv,
                                      WqkvT, WoT, W1T, W2T, bqkv);

    if (big) {
        bf16_t* ctx  = (bf16_t*)(ws + OFF_B);              // 64 MB [96,160)
        bf16_t* qkvc = (bf16_t*)(ws + OFF_B + 67108864);   // 50 MB [160,210.3)
        // 3. QKV + attention in 2-batch chunks (8192 rows)
        for (int c = 0; c < 4; ++c) {
            const size_t r0 = (size_t)c * 8192;
            k_gemm_bt<1><<<dim3(3072/BN, 8192/BM), 256, 0, stream>>>(
                Xb + r0*D_, WqkvT, bqkv, qkvc, 3072, 1024);
            k_attn<<<8192*H_/4, 256, 0, stream>>>(qkvc, mask + r0, ctx + r0*D_);
        }
        // 4. Y = ctx @ Wo + bo (fp32, into d_out)
        k_gemm_bt<0><<<dim3(1024/BN, MTOT/BM), 256, 0, stream>>>(ctx, WoT, bo, Y, 1024, 1024);
        // 5. X1 = LN(Xb + Y) -> Xb (in-place bf16)
        k_res_ln<0><<<MTOT, 256, 0, stream>>>(Xb, Y, g1, be1, Xb, nullptr);
        // 6. FFN in two 16K-row chunks
        bf16_t* hb = (bf16_t*)(ws + OFF_B);                // 128 MB [96,224)
        for (int c = 0; c < 2; ++c) {
            const size_t r0 = (size_t)c * 16384;
            k_gemm_bt<2><<<dim3(NFF/BN, 16384/BM), 256, 0, stream>>>(
                Xb + r0*D_, W1T, b1, hb, NFF, 1024);
            k_gemm_bt<0><<<dim3(1024/BN, 16384/BM), 256, 0, stream>>>(
                hb, W2T, b2, Y + r0*D_, 1024, NFF);
        }
        // 7. out = LN(X1 + Y) -> fp32 d_out (in-place over Y)
        k_res_ln<1><<<MTOT, 256, 0, stream>>>(Xb, Y, g2, be2, nullptr, (float*)d_out);
    } else {
        bf16_t* qkvc = (bf16_t*)(ws + OFF_B);              // 24 MB [96,120)
        bf16_t* ctxc = (bf16_t*)(ws + OFF_B + 25165824);   //  8 MB [120,128)
        for (int b = 0; b < B_; ++b) {
            const size_t r0 = (size_t)b * L_;
            k_gemm_bt<1><<<dim3(3072/BN, L_/BM), 256, 0, stream>>>(
                Xb + r0*D_, WqkvT, bqkv, qkvc, 3072, 1024);
            k_attn<<<L_*H_/4, 256, 0, stream>>>(qkvc, mask + r0, ctxc);
            k_gemm_bt<0><<<dim3(1024/BN, L_/BM), 256, 0, stream>>>(
                ctxc, WoT, bo, Y + r0*D_, 1024, 1024);
        }
        k_res_ln<0><<<MTOT, 256, 0, stream>>>(Xb, Y, g1, be1, Xb, nullptr);
        bf16_t* hb = (bf16_t*)(ws + OFF_B);                // 32 MB [96,128)
        for (int c = 0; c < 8; ++c) {
            const size_t r0 = (size_t)c * L_;
            k_gemm_bt<2><<<dim3(NFF/BN, L_/BM), 256, 0, stream>>>(
                Xb + r0*D_, W1T, b1, hb, NFF, 1024);
            k_gemm_bt<0><<<dim3(1024/BN, L_/BM), 256, 0, stream>>>(
                hb, W2T, b2, Y + r0*D_, 1024, NFF);
        }
        k_res_ln<1><<<MTOT, 256, 0, stream>>>(Xb, Y, g2, be2, nullptr, (float*)d_out);
    }
}